// Round 7
// baseline (410.577 us; speedup 1.0000x reference)
//
#include <hip/hip_runtime.h>
#include <stdint.h>

typedef short v8s __attribute__((ext_vector_type(8)));
typedef float v4f __attribute__((ext_vector_type(4)));
typedef uint16_t u16;

#define NB2   131072           // 262144 graphs / 2 per wave-iter
#define ALPHA 0.2f
#define NEGV  -9000000000000000.0f

__device__ __forceinline__ uint32_t bf16rne(float f) {
    uint32_t u = __float_as_uint(f);
    return (u + 0x7FFFu + ((u >> 16) & 1u)) >> 16;
}
__device__ __forceinline__ uint32_t pk2(float lo, float hi) {
    return bf16rne(lo) | (bf16rne(hi) << 16);
}

// ---- precompute: Wc = W2@W1@W0 (bf16 out), bc = W2@(W1@b0+b1)+b2 — R3 exact ----
__global__ __launch_bounds__(256) void gat_pre(
    const float* __restrict__ W0, const float* __restrict__ b0,
    const float* __restrict__ W1, const float* __restrict__ b1,
    const float* __restrict__ W2, const float* __restrict__ b2,
    float* __restrict__ bc_out, u16* __restrict__ wcb16)
{
    __shared__ float T[64 * 64];
    __shared__ float tb[64];
    const int t = threadIdx.x;
    for (int s = 0; s < 16; ++s) {
        int idx = t + 256 * s; int i = idx >> 6, j = idx & 63;
        float acc = 0.f;
        for (int k = 0; k < 64; ++k) acc = fmaf(W1[i * 64 + k], W0[k * 64 + j], acc);
        T[idx] = acc;
    }
    if (t < 64) {
        float acc = b1[t];
        for (int k = 0; k < 64; ++k) acc = fmaf(W1[t * 64 + k], b0[k], acc);
        tb[t] = acc;
    }
    __syncthreads();
    for (int s = 0; s < 16; ++s) {
        int idx = t + 256 * s; int i = idx >> 6, j = idx & 63;
        float acc = 0.f;
        for (int k = 0; k < 64; ++k) acc = fmaf(W2[i * 64 + k], T[k * 64 + j], acc);
        wcb16[idx] = (u16)bf16rne(acc);
    }
    if (t < 64) {
        float acc = b2[t];
        for (int k = 0; k < 64; ++k) acc = fmaf(W2[t * 64 + k], tb[k], acc);
        bc_out[t] = acc;
    }
}

// ---- main: slim 2-graph/wave-iter variant targeting <=64 VGPR, 32 waves/CU ----
// Wc lives in block-shared LDS, chunk-swizzled: row r (128 B = 8 chunks of 16B),
// chunk c stored at physical chunk c ^ (r&7). B-frag read (lane a_,h; chunk 4kt+h)
// then lands on 8 distinct bank-groups x2 lanes = 2-way (free).
__global__ __launch_bounds__(256, 8) void gat_main(
    const float* __restrict__ node, const int* __restrict__ adj,
    const float* __restrict__ a, const float* __restrict__ bc,
    const u16* __restrict__ wcb16, float* __restrict__ out)
{
    __shared__ u16      wc_lds[64 * 64];    // 8192 B (block-shared, swizzled)
    __shared__ float    a_sh[128];          // 512 B
    __shared__ u16      xtile[4][16 * 64];  // 8192 B (per-wave; rows 12-15 junk)
    __shared__ float    ebuf2[4][2][12];    // 384 B
    __shared__ uint32_t pbuf[4][12][4];     // 768 B

    const int tid  = threadIdx.x;
    const int w    = tid >> 6;
    const int lane = tid & 63;
    const int a_   = lane & 15;
    const int h    = lane >> 4;

    // ---- block init: stage Wc (swizzled) + a; one-time sync ----
    {
        #pragma unroll
        for (int m = 0; m < 2; ++m) {
            int flat = tid * 2 + m;                 // chunk id 0..511
            int r = flat >> 3, p = flat & 7;
            uint4 v = *(const uint4*)((const char*)wcb16 + flat * 16);
            *(uint4*)((char*)wc_lds + (size_t)(r * 8 + (p ^ (r & 7))) * 16) = v;
        }
        if (tid < 128) a_sh[tid] = a[tid];
    }
    __syncthreads();

    uint64_t amask = 0ull;
    #pragma unroll 1
    for (int ij = 0; ij < 36; ++ij) amask |= ((uint64_t)(adj[ij] & 1)) << ij;

    float bcl[4], a_s[4], a_d[4];
    #pragma unroll
    for (int n = 0; n < 4; ++n) {
        bcl[n] = bc[16 * n + a_];
        a_s[n] = a_sh[16 * n + a_];
        a_d[n] = a_sh[64 + 16 * n + a_];
    }

    u16*   xt  = &xtile[w][0];
    float* ebs = &ebuf2[w][0][0];
    float* ebd = &ebuf2[w][1][0];

    const int nwaves = (int)((gridDim.x * blockDim.x) >> 6);   // 8192
    const int wgid   = (int)((blockIdx.x * blockDim.x + tid) >> 6);

    // lane's node row within the 2-graph group (12 rows); a_>=12 clamped (junk rows)
    const int rowoff = (a_ < 12 ? a_ : 0) * 256;

    // preload first tile: pieces at bytes 32h+{0,16} (kt=0), 128+32h+{0,16} (kt=1)
    float4 Araw[4];
    {
        const char* nb = (const char*)node + (size_t)wgid * 3072 + rowoff + h * 32;
        Araw[0] = *(const float4*)(nb);
        Araw[1] = *(const float4*)(nb + 16);
        Araw[2] = *(const float4*)(nb + 128);
        Araw[3] = *(const float4*)(nb + 144);
    }

    #pragma unroll 1
    for (int g = wgid; g < NB2; g += nwaves) {
        // ---- pack A fragments (bf16) ----
        v8s A0, A1;
        {
            union { uint32_t u[4]; v8s v; } f;
            f.u[0] = pk2(Araw[0].x, Araw[0].y);
            f.u[1] = pk2(Araw[0].z, Araw[0].w);
            f.u[2] = pk2(Araw[1].x, Araw[1].y);
            f.u[3] = pk2(Araw[1].z, Araw[1].w);
            A0 = f.v;
            f.u[0] = pk2(Araw[2].x, Araw[2].y);
            f.u[1] = pk2(Araw[2].z, Araw[2].w);
            f.u[2] = pk2(Araw[3].x, Araw[3].y);
            f.u[3] = pk2(Araw[3].z, Araw[3].w);
            A1 = f.v;
        }
        // ---- prefetch next group (skip last iter; wave-uniform) ----
        if (g + nwaves < NB2) {
            const char* nb = (const char*)node + (size_t)(g + nwaves) * 3072 + rowoff + h * 32;
            Araw[0] = *(const float4*)(nb);
            Araw[1] = *(const float4*)(nb + 16);
            Araw[2] = *(const float4*)(nb + 128);
            Araw[3] = *(const float4*)(nb + 144);
        }

        // ---- P1: X = node@Wc^T + bc (one 16x64 MFMA tile); e-partials in regs ----
        float es_p[4] = { 0.f, 0.f, 0.f, 0.f };
        float ed_p[4] = { 0.f, 0.f, 0.f, 0.f };
        #pragma unroll
        for (int n = 0; n < 4; ++n) {
            const char* wrow = (const char*)wc_lds + (16 * n + a_) * 128;
            v8s b0 = *(const v8s*)(wrow + (((h    ) ^ (a_ & 7)) << 4));
            v8s b1 = *(const v8s*)(wrow + (((4 + h) ^ (a_ & 7)) << 4));
            v4f acc = { bcl[n], bcl[n], bcl[n], bcl[n] };
            acc = __builtin_amdgcn_mfma_f32_16x16x32_bf16(A0, b0, acc, 0, 0, 0);
            acc = __builtin_amdgcn_mfma_f32_16x16x32_bf16(A1, b1, acc, 0, 0, 0);
            uint32_t p01 = pk2(acc[0], acc[1]);
            uint32_t p23 = pk2(acc[2], acc[3]);
            const int cb = (16 * n + a_) ^ (h << 4);   // swizzled physical col
            const int rb = (4 * h) * 64 + cb;          // rows 4h+r
            xt[rb]       = (u16)p01;
            xt[rb + 64]  = (u16)(p01 >> 16);
            xt[rb + 128] = (u16)p23;
            xt[rb + 192] = (u16)(p23 >> 16);
            #pragma unroll
            for (int r = 0; r < 4; ++r) {
                es_p[r] = fmaf(acc[r], a_s[n], es_p[r]);
                ed_p[r] = fmaf(acc[r], a_d[n], ed_p[r]);
            }
        }
        // reduce over the 16-lane column group
        #pragma unroll
        for (int r = 0; r < 4; ++r) {
            #pragma unroll
            for (int m = 8; m > 0; m >>= 1) {
                es_p[r] += __shfl_xor(es_p[r], m, 16);
                ed_p[r] += __shfl_xor(ed_p[r], m, 16);
            }
        }
        if (a_ == 0) {
            #pragma unroll
            for (int r = 0; r < 4; ++r) { int row = 4 * h + r; if (row < 12) ebs[row] = es_p[r]; }
        }
        if (a_ == 1) {
            #pragma unroll
            for (int r = 0; r < 4; ++r) { int row = 4 * h + r; if (row < 12) ebd[row] = ed_p[r]; }
        }
        asm volatile("s_waitcnt lgkmcnt(0)" ::: "memory");
        __builtin_amdgcn_sched_barrier(0);

        // ---- P3: masked softmax per row (lane = row, 12 active) ----
        if (lane < 12) {
            const int bb = lane / 6;
            const int i6 = lane - 6 * bb;
            float es = ebs[lane];
            float ed[6];
            #pragma unroll
            for (int k = 0; k < 3; ++k)
                *(float2*)&ed[2 * k] = *(const float2*)(ebd + 6 * bb + 2 * k);
            uint32_t rm = (uint32_t)((amask >> (i6 * 6)) & 63u);
            float l[6];
            #pragma unroll
            for (int j = 0; j < 6; ++j) {
                float z  = es + ed[j];
                float lk = fmaxf(z, ALPHA * z);
                l[j] = (rm & (1u << j)) ? lk : NEGV;
            }
            float mm = fmaxf(fmaxf(fmaxf(l[0], l[1]), fmaxf(l[2], l[3])), fmaxf(l[4], l[5]));
            float p[6]; float sum = 0.f;
            #pragma unroll
            for (int j = 0; j < 6; ++j) { p[j] = __expf(l[j] - mm); sum += p[j]; }
            float inv = 1.0f / sum;
            uint4 pk;
            pk.x = pk2(p[0] * inv, p[1] * inv);
            pk.y = pk2(p[2] * inv, p[3] * inv);
            pk.z = pk2(p[4] * inv, p[5] * inv);
            pk.w = 0u;
            *(uint4*)&pbuf[w][lane][0] = pk;
        }
        asm volatile("s_waitcnt lgkmcnt(0)" ::: "memory");
        __builtin_amdgcn_sched_barrier(0);

        // ---- P4: out[i][lane] = sum_j p[i][j] * x[j][lane] (2 graphs) ----
        #pragma unroll
        for (int bb = 0; bb < 2; ++bb) {
            float xr[6];
            #pragma unroll
            for (int jj = 0; jj < 6; ++jj) {
                int rj = 6 * bb + jj;
                u16 xv = xt[rj * 64 + (lane ^ ((((rj >> 2) & 3)) << 4))];
                xr[jj] = __uint_as_float(((uint32_t)xv) << 16);
            }
            float* dst = out + ((size_t)(g * 2 + bb)) * 384 + lane;
            #pragma unroll
            for (int i2 = 0; i2 < 6; ++i2) {
                uint4 pu = *(const uint4*)&pbuf[w][bb * 6 + i2][0];
                float p0 = __uint_as_float(pu.x << 16);
                float p1 = __uint_as_float(pu.x & 0xFFFF0000u);
                float p2 = __uint_as_float(pu.y << 16);
                float p3 = __uint_as_float(pu.y & 0xFFFF0000u);
                float p4 = __uint_as_float(pu.z << 16);
                float p5 = __uint_as_float(pu.z & 0xFFFF0000u);
                float o = p0 * xr[0];
                o = fmaf(p1, xr[1], o);
                o = fmaf(p2, xr[2], o);
                o = fmaf(p3, xr[3], o);
                o = fmaf(p4, xr[4], o);
                o = fmaf(p5, xr[5], o);
                dst[i2 * 64] = o;
            }
        }
        asm volatile("s_waitcnt lgkmcnt(0)" ::: "memory");  // WAR vs next P1
        __builtin_amdgcn_sched_barrier(0);
    }
}

extern "C" void kernel_launch(void* const* d_in, const int* in_sizes, int n_in,
                              void* d_out, int out_size, void* d_ws, size_t ws_size,
                              hipStream_t stream)
{
    const float* node = (const float*)d_in[0];
    const int*   adj  = (const int*)d_in[1];
    const float* W0   = (const float*)d_in[2];
    const float* b0   = (const float*)d_in[3];
    const float* W1   = (const float*)d_in[4];
    const float* b1   = (const float*)d_in[5];
    const float* W2   = (const float*)d_in[6];
    const float* b2   = (const float*)d_in[7];
    const float* a    = (const float*)d_in[8];
    float* outp = (float*)d_out;

    float* wsf   = (float*)d_ws;
    float* bcp   = wsf;                      // 64 f32
    u16*   wcb16 = (u16*)(wsf + 64);         // 4096 u16 (16B-aligned)

    gat_pre<<<1, 256, 0, stream>>>(W0, b0, W1, b1, W2, b2, bcp, wcb16);
    gat_main<<<2048, 256, 0, stream>>>(node, adj, a, bcp, wcb16, outp);
}

// Round 8
// 203.728 us; speedup vs baseline: 2.0153x; 2.0153x over previous
//
#include <hip/hip_runtime.h>
#include <stdint.h>

typedef short v8s __attribute__((ext_vector_type(8)));
typedef float v4f __attribute__((ext_vector_type(4)));
typedef uint16_t u16;

#define NB8   32768            // 262144 / 8 graphs per wave-iter
#define ALPHA 0.2f
#define NEGV  -9000000000000000.0f

__device__ __forceinline__ uint32_t bf16rne(float f) {
    uint32_t u = __float_as_uint(f);
    return (u + 0x7FFFu + ((u >> 16) & 1u)) >> 16;
}
__device__ __forceinline__ uint32_t pk2(float lo, float hi) {
    return bf16rne(lo) | (bf16rne(hi) << 16);
}

// ---- precompute: Wc = W2@W1@W0 (bf16 out), bc = W2@(W1@b0+b1)+b2 — R3 exact ----
__global__ __launch_bounds__(256) void gat_pre(
    const float* __restrict__ W0, const float* __restrict__ b0,
    const float* __restrict__ W1, const float* __restrict__ b1,
    const float* __restrict__ W2, const float* __restrict__ b2,
    float* __restrict__ bc_out, u16* __restrict__ wcb16)
{
    __shared__ float T[64 * 64];
    __shared__ float tb[64];
    const int t = threadIdx.x;
    for (int s = 0; s < 16; ++s) {
        int idx = t + 256 * s; int i = idx >> 6, j = idx & 63;
        float acc = 0.f;
        for (int k = 0; k < 64; ++k) acc = fmaf(W1[i * 64 + k], W0[k * 64 + j], acc);
        T[idx] = acc;
    }
    if (t < 64) {
        float acc = b1[t];
        for (int k = 0; k < 64; ++k) acc = fmaf(W1[t * 64 + k], b0[k], acc);
        tb[t] = acc;
    }
    __syncthreads();
    for (int s = 0; s < 16; ++s) {
        int idx = t + 256 * s; int i = idx >> 6, j = idx & 63;
        float acc = 0.f;
        for (int k = 0; k < 64; ++k) acc = fmaf(W2[i * 64 + k], T[k * 64 + j], acc);
        wcb16[idx] = (u16)bf16rne(acc);
    }
    if (t < 64) {
        float acc = b2[t];
        for (int k = 0; k < 64; ++k) acc = fmaf(W2[t * 64 + k], tb[k], acc);
        bc_out[t] = acc;
    }
}

// ---- main: R6 kernel; ONLY delta = P4 remapped to 8-lanes-per-graph with
//      ds_read_b128 + float4 stores, straight-line (enables counted vmcnt) ----
__global__ __launch_bounds__(256, 2) void gat_main(
    const float* __restrict__ node, const int* __restrict__ adj,
    const float* __restrict__ a, const float* __restrict__ bc,
    const u16* __restrict__ wcb16, float* __restrict__ out)
{
    // X tile bf16: row j (0..47), physical col = c ^ (16*((j>>2)&3))
    __shared__ u16      xtile[4][48 * 64];  // 24576 B
    __shared__ float    ebuf2[4][2][48];    // 1536 B: [0]=e_src, [1]=e_dst per row
    __shared__ uint32_t pbuf[4][48][4];     // 3072 B: softmax rows packed bf16

    const int tid  = threadIdx.x;
    const int w    = tid >> 6;
    const int lane = tid & 63;
    const int a_   = lane & 15;
    const int h    = lane >> 4;

    uint64_t amask = 0ull;
    #pragma unroll 1
    for (int ij = 0; ij < 36; ++ij) amask |= ((uint64_t)(adj[ij] & 1)) << ij;

    // B fragments: B[k=32kt+8h+e][col=16n+a_] = Wc[16n+a_][k]
    v8s Bw[4][2];
    #pragma unroll
    for (int n = 0; n < 4; ++n)
        #pragma unroll
        for (int kt = 0; kt < 2; ++kt)
            Bw[n][kt] = *(const v8s*)(wcb16 + (16 * n + a_) * 64 + 32 * kt + 8 * h);
    float bcl[4], a_s[4], a_d[4];
    #pragma unroll
    for (int n = 0; n < 4; ++n) {
        bcl[n] = bc[16 * n + a_];
        a_s[n] = a[16 * n + a_];
        a_d[n] = a[64 + 16 * n + a_];
    }

    u16*   xt  = &xtile[w][0];
    float* ebs = &ebuf2[w][0][0];
    float* ebd = &ebuf2[w][1][0];

    const int nwaves = (int)((gridDim.x * blockDim.x) >> 6);
    const int wgid   = (int)((blockIdx.x * blockDim.x + tid) >> 6);

    // preload first tile: lane holds node[row=16t+a_][k=32kt+8h .. +8] (f32)
    float4 Araw[3][2][2];
    {
        const char* nb = (const char*)node + (size_t)wgid * 12288 + a_ * 256 + h * 32;
        #pragma unroll
        for (int t = 0; t < 3; ++t) {
            const char* bt = nb + t * 4096;
            Araw[t][0][0] = *(const float4*)(bt);
            Araw[t][0][1] = *(const float4*)(bt + 16);
            Araw[t][1][0] = *(const float4*)(bt + 128);
            Araw[t][1][1] = *(const float4*)(bt + 144);
        }
    }

    #pragma unroll 1
    for (int g = wgid; g < NB8; g += nwaves) {
        // ---- pack A fragments (bf16, pure C rne) ----
        v8s A[3][2];
        #pragma unroll
        for (int t = 0; t < 3; ++t)
            #pragma unroll
            for (int kt = 0; kt < 2; ++kt) {
                union { uint32_t u[4]; v8s v; } f;
                f.u[0] = pk2(Araw[t][kt][0].x, Araw[t][kt][0].y);
                f.u[1] = pk2(Araw[t][kt][0].z, Araw[t][kt][0].w);
                f.u[2] = pk2(Araw[t][kt][1].x, Araw[t][kt][1].y);
                f.u[3] = pk2(Araw[t][kt][1].z, Araw[t][kt][1].w);
                A[t][kt] = f.v;
            }
        // ---- prefetch next tile (skip on last iter; wave-uniform branch) ----
        if (g + nwaves < NB8) {
            const char* nb = (const char*)node + (size_t)(g + nwaves) * 12288 + a_ * 256 + h * 32;
            #pragma unroll
            for (int t = 0; t < 3; ++t) {
                const char* bt = nb + t * 4096;
                Araw[t][0][0] = *(const float4*)(bt);
                Araw[t][0][1] = *(const float4*)(bt + 16);
                Araw[t][1][0] = *(const float4*)(bt + 128);
                Araw[t][1][1] = *(const float4*)(bt + 144);
            }
        }

        // ---- P1: X = node@Wc^T + bc via MFMA -> bf16 tile; e-partials in regs ----
        #pragma unroll
        for (int t = 0; t < 3; ++t) {
            float es_p[4] = { 0.f, 0.f, 0.f, 0.f };
            float ed_p[4] = { 0.f, 0.f, 0.f, 0.f };
            #pragma unroll
            for (int n = 0; n < 4; ++n) {
                v4f acc = { bcl[n], bcl[n], bcl[n], bcl[n] };
                acc = __builtin_amdgcn_mfma_f32_16x16x32_bf16(A[t][0], Bw[n][0], acc, 0, 0, 0);
                acc = __builtin_amdgcn_mfma_f32_16x16x32_bf16(A[t][1], Bw[n][1], acc, 0, 0, 0);
                uint32_t p01 = pk2(acc[0], acc[1]);
                uint32_t p23 = pk2(acc[2], acc[3]);
                const int cb = (16 * n + a_) ^ (h << 4);      // swizzled physical col
                const int rb = (16 * t + 4 * h) * 64 + cb;    // rows 16t+4h+r
                xt[rb]       = (u16)p01;
                xt[rb + 64]  = (u16)(p01 >> 16);
                xt[rb + 128] = (u16)p23;
                xt[rb + 192] = (u16)(p23 >> 16);
                #pragma unroll
                for (int r = 0; r < 4; ++r) {
                    es_p[r] = fmaf(acc[r], a_s[n], es_p[r]);
                    ed_p[r] = fmaf(acc[r], a_d[n], ed_p[r]);
                }
            }
            // reduce over the 16-lane column group (a_ = 0..15)
            #pragma unroll
            for (int r = 0; r < 4; ++r) {
                #pragma unroll
                for (int m = 8; m > 0; m >>= 1) {
                    es_p[r] += __shfl_xor(es_p[r], m, 16);
                    ed_p[r] += __shfl_xor(ed_p[r], m, 16);
                }
            }
            if (a_ == 0) {
                #pragma unroll
                for (int r = 0; r < 4; ++r) ebs[16 * t + 4 * h + r] = es_p[r];
            }
            if (a_ == 1) {
                #pragma unroll
                for (int r = 0; r < 4; ++r) ebd[16 * t + 4 * h + r] = ed_p[r];
            }
        }
        asm volatile("s_waitcnt lgkmcnt(0)" ::: "memory");
        __builtin_amdgcn_sched_barrier(0);

        // ---- P3: masked softmax per row (lane = row, 48 active) ----
        if (lane < 48) {
            const int bb = lane / 6;
            const int i6 = lane - 6 * bb;
            float es = ebs[lane];
            float ed[6];
            #pragma unroll
            for (int k = 0; k < 3; ++k)
                *(float2*)&ed[2 * k] = *(const float2*)(ebd + 6 * bb + 2 * k);
            uint32_t rm = (uint32_t)((amask >> (i6 * 6)) & 63u);
            float l[6];
            #pragma unroll
            for (int j = 0; j < 6; ++j) {
                float z  = es + ed[j];
                float lk = fmaxf(z, ALPHA * z);
                l[j] = (rm & (1u << j)) ? lk : NEGV;
            }
            float mm = fmaxf(fmaxf(fmaxf(l[0], l[1]), fmaxf(l[2], l[3])), fmaxf(l[4], l[5]));
            float p[6]; float sum = 0.f;
            #pragma unroll
            for (int j = 0; j < 6; ++j) { p[j] = __expf(l[j] - mm); sum += p[j]; }
            float inv = 1.0f / sum;
            uint4 pk;
            pk.x = pk2(p[0] * inv, p[1] * inv);
            pk.y = pk2(p[2] * inv, p[3] * inv);
            pk.z = pk2(p[4] * inv, p[5] * inv);
            pk.w = 0u;
            *(uint4*)&pbuf[w][lane][0] = pk;
        }
        asm volatile("s_waitcnt lgkmcnt(0)" ::: "memory");
        __builtin_amdgcn_sched_barrier(0);

        // ---- P4: out = P@X; lane (b=lane>>3, q=lane&7) owns cols 8q..8q+7 of
        //      graph b. 6 b128 X reads + 6 broadcast b128 p reads + 12 float4
        //      stores. Straight-line: waitcnt pass can count stores precisely. ----
        {
            const int b = lane >> 3;
            const int q = lane & 7;
            union { uint4 v; u16 s[8]; } xu[6];
            #pragma unroll
            for (int j = 0; j < 6; ++j) {
                int rj = 6 * b + j;
                int cp = (8 * q) ^ ((((rj >> 2) & 3)) << 4);   // physical col (8-contig)
                xu[j].v = *(const uint4*)(xt + rj * 64 + cp);
            }
            float* dst = out + ((size_t)(g * 8 + b)) * 384 + 8 * q;
            #pragma unroll
            for (int i2 = 0; i2 < 6; ++i2) {
                uint4 pu = *(const uint4*)&pbuf[w][6 * b + i2][0];
                float p[6];
                p[0] = __uint_as_float(pu.x << 16);
                p[1] = __uint_as_float(pu.x & 0xFFFF0000u);
                p[2] = __uint_as_float(pu.y << 16);
                p[3] = __uint_as_float(pu.y & 0xFFFF0000u);
                p[4] = __uint_as_float(pu.z << 16);
                p[5] = __uint_as_float(pu.z & 0xFFFF0000u);
                float o[8];
                #pragma unroll
                for (int c = 0; c < 8; ++c) {
                    float acc0 = p[0] * __uint_as_float(((uint32_t)xu[0].s[c]) << 16);
                    acc0 = fmaf(p[1], __uint_as_float(((uint32_t)xu[1].s[c]) << 16), acc0);
                    acc0 = fmaf(p[2], __uint_as_float(((uint32_t)xu[2].s[c]) << 16), acc0);
                    acc0 = fmaf(p[3], __uint_as_float(((uint32_t)xu[3].s[c]) << 16), acc0);
                    acc0 = fmaf(p[4], __uint_as_float(((uint32_t)xu[4].s[c]) << 16), acc0);
                    acc0 = fmaf(p[5], __uint_as_float(((uint32_t)xu[5].s[c]) << 16), acc0);
                    o[c] = acc0;
                }
                float4 o0 = { o[0], o[1], o[2], o[3] };
                float4 o1 = { o[4], o[5], o[6], o[7] };
                *(float4*)(dst + i2 * 64)     = o0;
                *(float4*)(dst + i2 * 64 + 4) = o1;
            }
        }
        asm volatile("s_waitcnt lgkmcnt(0)" ::: "memory");  // WAR vs next P1
        __builtin_amdgcn_sched_barrier(0);
    }
}

extern "C" void kernel_launch(void* const* d_in, const int* in_sizes, int n_in,
                              void* d_out, int out_size, void* d_ws, size_t ws_size,
                              hipStream_t stream)
{
    const float* node = (const float*)d_in[0];
    const int*   adj  = (const int*)d_in[1];
    const float* W0   = (const float*)d_in[2];
    const float* b0   = (const float*)d_in[3];
    const float* W1   = (const float*)d_in[4];
    const float* b1   = (const float*)d_in[5];
    const float* W2   = (const float*)d_in[6];
    const float* b2   = (const float*)d_in[7];
    const float* a    = (const float*)d_in[8];
    float* outp = (float*)d_out;

    float* wsf   = (float*)d_ws;
    float* bcp   = wsf;                      // 64 f32
    u16*   wcb16 = (u16*)(wsf + 64);         // 4096 u16 (16B-aligned)

    gat_pre<<<1, 256, 0, stream>>>(W0, b0, W1, b1, W2, b2, bcp, wcb16);
    gat_main<<<1024, 256, 0, stream>>>(node, adj, a, bcp, wcb16, outp);
}

// Round 10
// 201.814 us; speedup vs baseline: 2.0344x; 1.0095x over previous
//
#include <hip/hip_runtime.h>
#include <stdint.h>

typedef short v8s __attribute__((ext_vector_type(8)));
typedef float v4f __attribute__((ext_vector_type(4)));
typedef uint16_t u16;

#define NB8   32768            // 262144 / 8 graphs per wave-iter
#define ALPHA 0.2f
#define NEGV  -9000000000000000.0f

__device__ __forceinline__ uint32_t bf16rne(float f) {
    uint32_t u = __float_as_uint(f);
    return (u + 0x7FFFu + ((u >> 16) & 1u)) >> 16;
}
__device__ __forceinline__ uint32_t pk2(float lo, float hi) {
    return bf16rne(lo) | (bf16rne(hi) << 16);
}

// ---- precompute: Wc = W2@W1@W0 (bf16 out), bc = W2@(W1@b0+b1)+b2 — R3 exact ----
__global__ __launch_bounds__(256) void gat_pre(
    const float* __restrict__ W0, const float* __restrict__ b0,
    const float* __restrict__ W1, const float* __restrict__ b1,
    const float* __restrict__ W2, const float* __restrict__ b2,
    float* __restrict__ bc_out, u16* __restrict__ wcb16)
{
    __shared__ float T[64 * 64];
    __shared__ float tb[64];
    const int t = threadIdx.x;
    for (int s = 0; s < 16; ++s) {
        int idx = t + 256 * s; int i = idx >> 6, j = idx & 63;
        float acc = 0.f;
        for (int k = 0; k < 64; ++k) acc = fmaf(W1[i * 64 + k], W0[k * 64 + j], acc);
        T[idx] = acc;
    }
    if (t < 64) {
        float acc = b1[t];
        for (int k = 0; k < 64; ++k) acc = fmaf(W1[t * 64 + k], b0[k], acc);
        tb[t] = acc;
    }
    __syncthreads();
    for (int s = 0; s < 16; ++s) {
        int idx = t + 256 * s; int i = idx >> 6, j = idx & 63;
        float acc = 0.f;
        for (int k = 0; k < 64; ++k) acc = fmaf(W2[i * 64 + k], T[k * 64 + j], acc);
        wcb16[idx] = (u16)bf16rne(acc);
    }
    if (t < 64) {
        float acc = b2[t];
        for (int k = 0; k < 64; ++k) acc = fmaf(W2[t * 64 + k], tb[k], acc);
        bc_out[t] = acc;
    }
}

// ---- main: R8 kernel; deltas = {no intra-loop fences, nontemporal node
//      loads, nontemporal out stores} — nt ops now use clang ext_vector v4f ----
__global__ __launch_bounds__(256, 2) void gat_main(
    const float* __restrict__ node, const int* __restrict__ adj,
    const float* __restrict__ a, const float* __restrict__ bc,
    const u16* __restrict__ wcb16, float* __restrict__ out)
{
    // X tile bf16: row j (0..47), physical col = c ^ (16*((j>>2)&3))
    __shared__ u16      xtile[4][48 * 64];  // 24576 B
    __shared__ float    ebuf2[4][2][48];    // 1536 B: [0]=e_src, [1]=e_dst per row
    __shared__ uint32_t pbuf[4][48][4];     // 3072 B: softmax rows packed bf16

    const int tid  = threadIdx.x;
    const int w    = tid >> 6;
    const int lane = tid & 63;
    const int a_   = lane & 15;
    const int h    = lane >> 4;

    uint64_t amask = 0ull;
    #pragma unroll 1
    for (int ij = 0; ij < 36; ++ij) amask |= ((uint64_t)(adj[ij] & 1)) << ij;

    // B fragments: B[k=32kt+8h+e][col=16n+a_] = Wc[16n+a_][k]
    v8s Bw[4][2];
    #pragma unroll
    for (int n = 0; n < 4; ++n)
        #pragma unroll
        for (int kt = 0; kt < 2; ++kt)
            Bw[n][kt] = *(const v8s*)(wcb16 + (16 * n + a_) * 64 + 32 * kt + 8 * h);
    float bcl[4], a_s[4], a_d[4];
    #pragma unroll
    for (int n = 0; n < 4; ++n) {
        bcl[n] = bc[16 * n + a_];
        a_s[n] = a[16 * n + a_];
        a_d[n] = a[64 + 16 * n + a_];
    }

    u16*   xt  = &xtile[w][0];
    float* ebs = &ebuf2[w][0][0];
    float* ebd = &ebuf2[w][1][0];

    const int nwaves = (int)((gridDim.x * blockDim.x) >> 6);
    const int wgid   = (int)((blockIdx.x * blockDim.x + tid) >> 6);

    // preload first tile: lane holds node[row=16t+a_][k=32kt+8h .. +8] (f32)
    v4f Araw[3][2][2];
    {
        const char* nb = (const char*)node + (size_t)wgid * 12288 + a_ * 256 + h * 32;
        #pragma unroll
        for (int t = 0; t < 3; ++t) {
            const char* bt = nb + t * 4096;
            Araw[t][0][0] = __builtin_nontemporal_load((const v4f*)(bt));
            Araw[t][0][1] = __builtin_nontemporal_load((const v4f*)(bt + 16));
            Araw[t][1][0] = __builtin_nontemporal_load((const v4f*)(bt + 128));
            Araw[t][1][1] = __builtin_nontemporal_load((const v4f*)(bt + 144));
        }
    }

    #pragma unroll 1
    for (int g = wgid; g < NB8; g += nwaves) {
        // ---- pack A fragments (bf16, pure C rne) ----
        v8s A[3][2];
        #pragma unroll
        for (int t = 0; t < 3; ++t)
            #pragma unroll
            for (int kt = 0; kt < 2; ++kt) {
                union { uint32_t u[4]; v8s v; } f;
                f.u[0] = pk2(Araw[t][kt][0][0], Araw[t][kt][0][1]);
                f.u[1] = pk2(Araw[t][kt][0][2], Araw[t][kt][0][3]);
                f.u[2] = pk2(Araw[t][kt][1][0], Araw[t][kt][1][1]);
                f.u[3] = pk2(Araw[t][kt][1][2], Araw[t][kt][1][3]);
                A[t][kt] = f.v;
            }
        // ---- prefetch next tile (skip on last iter; wave-uniform branch) ----
        if (g + nwaves < NB8) {
            const char* nb = (const char*)node + (size_t)(g + nwaves) * 12288 + a_ * 256 + h * 32;
            #pragma unroll
            for (int t = 0; t < 3; ++t) {
                const char* bt = nb + t * 4096;
                Araw[t][0][0] = __builtin_nontemporal_load((const v4f*)(bt));
                Araw[t][0][1] = __builtin_nontemporal_load((const v4f*)(bt + 16));
                Araw[t][1][0] = __builtin_nontemporal_load((const v4f*)(bt + 128));
                Araw[t][1][1] = __builtin_nontemporal_load((const v4f*)(bt + 144));
            }
        }

        // ---- P1: X = node@Wc^T + bc via MFMA -> bf16 tile; e-partials in regs ----
        #pragma unroll
        for (int t = 0; t < 3; ++t) {
            float es_p[4] = { 0.f, 0.f, 0.f, 0.f };
            float ed_p[4] = { 0.f, 0.f, 0.f, 0.f };
            #pragma unroll
            for (int n = 0; n < 4; ++n) {
                v4f acc = { bcl[n], bcl[n], bcl[n], bcl[n] };
                acc = __builtin_amdgcn_mfma_f32_16x16x32_bf16(A[t][0], Bw[n][0], acc, 0, 0, 0);
                acc = __builtin_amdgcn_mfma_f32_16x16x32_bf16(A[t][1], Bw[n][1], acc, 0, 0, 0);
                uint32_t p01 = pk2(acc[0], acc[1]);
                uint32_t p23 = pk2(acc[2], acc[3]);
                const int cb = (16 * n + a_) ^ (h << 4);      // swizzled physical col
                const int rb = (16 * t + 4 * h) * 64 + cb;    // rows 16t+4h+r
                xt[rb]       = (u16)p01;
                xt[rb + 64]  = (u16)(p01 >> 16);
                xt[rb + 128] = (u16)p23;
                xt[rb + 192] = (u16)(p23 >> 16);
                #pragma unroll
                for (int r = 0; r < 4; ++r) {
                    es_p[r] = fmaf(acc[r], a_s[n], es_p[r]);
                    ed_p[r] = fmaf(acc[r], a_d[n], ed_p[r]);
                }
            }
            // reduce over the 16-lane column group (a_ = 0..15)
            #pragma unroll
            for (int r = 0; r < 4; ++r) {
                #pragma unroll
                for (int m = 8; m > 0; m >>= 1) {
                    es_p[r] += __shfl_xor(es_p[r], m, 16);
                    ed_p[r] += __shfl_xor(ed_p[r], m, 16);
                }
            }
            if (a_ == 0) {
                #pragma unroll
                for (int r = 0; r < 4; ++r) ebs[16 * t + 4 * h + r] = es_p[r];
            }
            if (a_ == 1) {
                #pragma unroll
                for (int r = 0; r < 4; ++r) ebd[16 * t + 4 * h + r] = ed_p[r];
            }
        }

        // ---- P3: masked softmax per row (lane = row, 48 active) ----
        // (LDS RAW safe: DS pipe is in-order within a wave; compiler inserts
        //  the lgkmcnt waits for the loaded values.)
        if (lane < 48) {
            const int bb = lane / 6;
            const int i6 = lane - 6 * bb;
            float es = ebs[lane];
            float ed[6];
            #pragma unroll
            for (int k = 0; k < 3; ++k)
                *(float2*)&ed[2 * k] = *(const float2*)(ebd + 6 * bb + 2 * k);
            uint32_t rm = (uint32_t)((amask >> (i6 * 6)) & 63u);
            float l[6];
            #pragma unroll
            for (int j = 0; j < 6; ++j) {
                float z  = es + ed[j];
                float lk = fmaxf(z, ALPHA * z);
                l[j] = (rm & (1u << j)) ? lk : NEGV;
            }
            float mm = fmaxf(fmaxf(fmaxf(l[0], l[1]), fmaxf(l[2], l[3])), fmaxf(l[4], l[5]));
            float p[6]; float sum = 0.f;
            #pragma unroll
            for (int j = 0; j < 6; ++j) { p[j] = __expf(l[j] - mm); sum += p[j]; }
            float inv = 1.0f / sum;
            uint4 pk;
            pk.x = pk2(p[0] * inv, p[1] * inv);
            pk.y = pk2(p[2] * inv, p[3] * inv);
            pk.z = pk2(p[4] * inv, p[5] * inv);
            pk.w = 0u;
            *(uint4*)&pbuf[w][lane][0] = pk;
        }

        // ---- P4: out = P@X; lane (b=lane>>3, q=lane&7) owns cols 8q..8q+7 of
        //      graph b. 6 b128 X reads + 6 broadcast b128 p reads + 12 nt
        //      v4f stores. ----
        {
            const int b = lane >> 3;
            const int q = lane & 7;
            union { uint4 v; u16 s[8]; } xu[6];
            #pragma unroll
            for (int j = 0; j < 6; ++j) {
                int rj = 6 * b + j;
                int cp = (8 * q) ^ ((((rj >> 2) & 3)) << 4);   // physical col (8-contig)
                xu[j].v = *(const uint4*)(xt + rj * 64 + cp);
            }
            float* dst = out + ((size_t)(g * 8 + b)) * 384 + 8 * q;
            #pragma unroll
            for (int i2 = 0; i2 < 6; ++i2) {
                uint4 pu = *(const uint4*)&pbuf[w][6 * b + i2][0];
                float p[6];
                p[0] = __uint_as_float(pu.x << 16);
                p[1] = __uint_as_float(pu.x & 0xFFFF0000u);
                p[2] = __uint_as_float(pu.y << 16);
                p[3] = __uint_as_float(pu.y & 0xFFFF0000u);
                p[4] = __uint_as_float(pu.z << 16);
                p[5] = __uint_as_float(pu.z & 0xFFFF0000u);
                float o[8];
                #pragma unroll
                for (int c = 0; c < 8; ++c) {
                    float acc0 = p[0] * __uint_as_float(((uint32_t)xu[0].s[c]) << 16);
                    acc0 = fmaf(p[1], __uint_as_float(((uint32_t)xu[1].s[c]) << 16), acc0);
                    acc0 = fmaf(p[2], __uint_as_float(((uint32_t)xu[2].s[c]) << 16), acc0);
                    acc0 = fmaf(p[3], __uint_as_float(((uint32_t)xu[3].s[c]) << 16), acc0);
                    acc0 = fmaf(p[4], __uint_as_float(((uint32_t)xu[4].s[c]) << 16), acc0);
                    acc0 = fmaf(p[5], __uint_as_float(((uint32_t)xu[5].s[c]) << 16), acc0);
                    o[c] = acc0;
                }
                v4f o0 = { o[0], o[1], o[2], o[3] };
                v4f o1 = { o[4], o[5], o[6], o[7] };
                __builtin_nontemporal_store(o0, (v4f*)(dst + i2 * 64));
                __builtin_nontemporal_store(o1, (v4f*)(dst + i2 * 64 + 4));
            }
        }
    }
}

extern "C" void kernel_launch(void* const* d_in, const int* in_sizes, int n_in,
                              void* d_out, int out_size, void* d_ws, size_t ws_size,
                              hipStream_t stream)
{
    const float* node = (const float*)d_in[0];
    const int*   adj  = (const int*)d_in[1];
    const float* W0   = (const float*)d_in[2];
    const float* b0   = (const float*)d_in[3];
    const float* W1   = (const float*)d_in[4];
    const float* b1   = (const float*)d_in[5];
    const float* W2   = (const float*)d_in[6];
    const float* b2   = (const float*)d_in[7];
    const float* a    = (const float*)d_in[8];
    float* outp = (float*)d_out;

    float* wsf   = (float*)d_ws;
    float* bcp   = wsf;                      // 64 f32
    u16*   wcb16 = (u16*)(wsf + 64);         // 4096 u16 (16B-aligned)

    gat_pre<<<1, 256, 0, stream>>>(W0, b0, W1, b1, W2, b2, bcp, wcb16);
    gat_main<<<1024, 256, 0, stream>>>(node, adj, a, bcp, wcb16, outp);
}